// Round 1
// baseline (123.586 us; speedup 1.0000x reference)
//
#include <hip/hip_runtime.h>

#define EPS 1e-5f

// Single fused kernel:
//  - BN folding recomputed per-thread (uniform; param loads are scalar s_loads,
//    ~75 VALU ops hidden under the memory stream) -> no serialized fold dispatch.
//  - 4 neighbors per thread: loads are 3x global_load_dwordx4 (48 B, 16B-aligned
//    since neighbor quad starts at byte 48*q), stores 8x b128 (128 B contiguous
//    per thread; all cache lines fully written within the store burst).
__global__ __launch_bounds__(256) void lse_kernel(
    const float*  __restrict__ coords,  // (B,N,3)
    const float4* __restrict__ nbr4,    // (B,N,K,3) viewed as float4[total*3/4]
    const float* __restrict__ W1, const float* __restrict__ g1,
    const float* __restrict__ b1, const float* __restrict__ m1,
    const float* __restrict__ v1,
    const float* __restrict__ W2, const float* __restrict__ g2,
    const float* __restrict__ b2, const float* __restrict__ m2,
    const float* __restrict__ v2,
    float4* __restrict__ out4,          // (B,N,K,8) as float4[total*2]
    int quads)                          // B*N*K/4
{
    int q = blockIdx.x * blockDim.x + threadIdx.x;
    if (q >= quads) return;

    // ---- fold BN into weights (uniform across all threads) ----
    float w1f[16], sh1[4];
#pragma unroll
    for (int o = 0; o < 4; ++o) {
        float s = g1[o] * rsqrtf(v1[o] + EPS);
#pragma unroll
        for (int c = 0; c < 4; ++c) w1f[o * 4 + c] = W1[o * 4 + c] * s;
        sh1[o] = b1[o] - m1[o] * s;
    }
    float w2f[32], sh2[8];
#pragma unroll
    for (int o = 0; o < 8; ++o) {
        float s = g2[o] * rsqrtf(v2[o] + EPS);
#pragma unroll
        for (int c = 0; c < 4; ++c) w2f[o * 4 + c] = W2[o * 4 + c] * s;
        sh2[o] = b2[o] - m2[o] * s;
    }

    // ---- load 4 neighbors (48 B) as three float4 ----
    int bn = q >> 2;                    // K = 16 -> 4 quads per point
    float cx = coords[bn * 3 + 0];
    float cy = coords[bn * 3 + 1];
    float cz = coords[bn * 3 + 2];

    float4 p0 = nbr4[(size_t)q * 3 + 0];
    float4 p1 = nbr4[(size_t)q * 3 + 1];
    float4 p2 = nbr4[(size_t)q * 3 + 2];
    float nb[12] = {p0.x, p0.y, p0.z, p0.w,
                    p1.x, p1.y, p1.z, p1.w,
                    p2.x, p2.y, p2.z, p2.w};

#pragma unroll
    for (int k = 0; k < 4; ++k) {
        float rx = nb[k * 3 + 0] - cx;
        float ry = nb[k * 3 + 1] - cy;
        float rz = nb[k * 3 + 2] - cz;
        float dist = sqrtf(rx * rx + ry * ry + rz * rz);
        float enc[4] = {rx, ry, rz, dist};

        float h[4];
#pragma unroll
        for (int o = 0; o < 4; ++o) {
            float a = sh1[o];
#pragma unroll
            for (int c = 0; c < 4; ++c) a = fmaf(w1f[o * 4 + c], enc[c], a);
            h[o] = fmaxf(a, 0.f);
        }

        float r[8];
#pragma unroll
        for (int o = 0; o < 8; ++o) {
            float a = sh2[o];
#pragma unroll
            for (int c = 0; c < 4; ++c) a = fmaf(w2f[o * 4 + c], h[c], a);
            r[o] = fmaxf(a, 0.f);
        }

        out4[(size_t)q * 8 + k * 2 + 0] = make_float4(r[0], r[1], r[2], r[3]);
        out4[(size_t)q * 8 + k * 2 + 1] = make_float4(r[4], r[5], r[6], r[7]);
    }
}

extern "C" void kernel_launch(void* const* d_in, const int* in_sizes, int n_in,
                              void* d_out, int out_size, void* d_ws, size_t ws_size,
                              hipStream_t stream) {
    const float* coords = (const float*)d_in[0];
    const float* nbr    = (const float*)d_in[1];
    float* out = (float*)d_out;

    int total = in_sizes[1] / 3;        // B*N*K
    int quads = total >> 2;             // 4 neighbors per thread
    int block = 256;
    int grid = (quads + block - 1) / block;
    lse_kernel<<<grid, block, 0, stream>>>(
        coords, (const float4*)nbr,
        (const float*)d_in[2], (const float*)d_in[3], (const float*)d_in[4],
        (const float*)d_in[5], (const float*)d_in[6],
        (const float*)d_in[7], (const float*)d_in[8], (const float*)d_in[9],
        (const float*)d_in[10], (const float*)d_in[11],
        (float4*)out, quads);
}

// Round 2
// 118.540 us; speedup vs baseline: 1.0426x; 1.0426x over previous
//
#include <hip/hip_runtime.h>

#define EPS 1e-5f

// Force a wave-uniform value into an SGPR (all lanes computed the same thing).
__device__ __forceinline__ float rfl(float x) {
    return __int_as_float(__builtin_amdgcn_readfirstlane(__float_as_int(x)));
}

// Single fused kernel, round-0 hot-loop structure preserved:
//  - 1 thread per (b,n,k) neighbor per grid-stride iteration:
//    loads 3x b32 (12-B lane stride), stores 2x b128 (32-B lane stride).
//  - BN fold computed once per wave BEFORE the loop (no divergence yet),
//    results pinned to SGPRs via readfirstlane -> hot loop's VGPR count
//    stays low (round-1's regression was VGPR/occupancy collapse from
//    keeping 60 uniform floats + 4-neighbor state in VGPRs).
//  - grid-stride (4 iters/thread) amortizes the fold preamble 4x; each
//    iteration's tid window is contiguous -> identical coalescing to round-0.
__global__ __launch_bounds__(256) void lse_kernel(
    const float* __restrict__ coords,   // (B,N,3)
    const float* __restrict__ nbr,      // (B,N,K,3)
    const float* __restrict__ W1, const float* __restrict__ g1,
    const float* __restrict__ b1, const float* __restrict__ m1,
    const float* __restrict__ v1,
    const float* __restrict__ W2, const float* __restrict__ g2,
    const float* __restrict__ b2, const float* __restrict__ m2,
    const float* __restrict__ v2,
    float* __restrict__ out,            // (B,N,K,8)
    int total)                          // B*N*K
{
    // ---- wave-uniform BN fold -> SGPRs (all lanes active here) ----
    float w1f[16], sh1[4], w2f[32], sh2[8];
#pragma unroll
    for (int o = 0; o < 4; ++o) {
        float s = g1[o] * rsqrtf(v1[o] + EPS);
#pragma unroll
        for (int c = 0; c < 4; ++c) w1f[o * 4 + c] = rfl(W1[o * 4 + c] * s);
        sh1[o] = rfl(b1[o] - m1[o] * s);
    }
#pragma unroll
    for (int o = 0; o < 8; ++o) {
        float s = g2[o] * rsqrtf(v2[o] + EPS);
#pragma unroll
        for (int c = 0; c < 4; ++c) w2f[o * 4 + c] = rfl(W2[o * 4 + c] * s);
        sh2[o] = rfl(b2[o] - m2[o] * s);
    }

    const int stride = gridDim.x * blockDim.x;
    for (int tid = blockIdx.x * blockDim.x + threadIdx.x; tid < total; tid += stride) {
        // encoding
        int bn = tid >> 4;  // K = 16
        float cx = coords[bn * 3 + 0];
        float cy = coords[bn * 3 + 1];
        float cz = coords[bn * 3 + 2];
        float rx = nbr[(size_t)tid * 3 + 0] - cx;
        float ry = nbr[(size_t)tid * 3 + 1] - cy;
        float rz = nbr[(size_t)tid * 3 + 2] - cz;
        float dist = sqrtf(rx * rx + ry * ry + rz * rz);
        float enc[4] = {rx, ry, rz, dist};

        // layer 1: 4 -> 4 (BN folded), ReLU
        float h[4];
#pragma unroll
        for (int o = 0; o < 4; ++o) {
            float a = sh1[o];
#pragma unroll
            for (int c = 0; c < 4; ++c) a = fmaf(w1f[o * 4 + c], enc[c], a);
            h[o] = fmaxf(a, 0.f);
        }

        // layer 2: 4 -> 8 (BN folded), ReLU
        float r[8];
#pragma unroll
        for (int o = 0; o < 8; ++o) {
            float a = sh2[o];
#pragma unroll
            for (int c = 0; c < 4; ++c) a = fmaf(w2f[o * 4 + c], h[c], a);
            r[o] = fmaxf(a, 0.f);
        }

        // store 32 B as two float4
        float4* op = (float4*)(out + (size_t)tid * 8);
        op[0] = make_float4(r[0], r[1], r[2], r[3]);
        op[1] = make_float4(r[4], r[5], r[6], r[7]);
    }
}

extern "C" void kernel_launch(void* const* d_in, const int* in_sizes, int n_in,
                              void* d_out, int out_size, void* d_ws, size_t ws_size,
                              hipStream_t stream) {
    const float* coords = (const float*)d_in[0];
    const float* nbr    = (const float*)d_in[1];
    float* out = (float*)d_out;

    int total = in_sizes[1] / 3;  // B*N*K
    int block = 256;
    int grid  = 2048;             // 524288 threads -> 4 grid-stride iters, no tail divergence
    lse_kernel<<<grid, block, 0, stream>>>(
        coords, nbr,
        (const float*)d_in[2], (const float*)d_in[3], (const float*)d_in[4],
        (const float*)d_in[5], (const float*)d_in[6],
        (const float*)d_in[7], (const float*)d_in[8], (const float*)d_in[9],
        (const float*)d_in[10], (const float*)d_in[11],
        out, total);
}